// Round 3
// baseline (17216.147 us; speedup 1.0000x reference)
//
#include <hip/hip_runtime.h>
#include <stdint.h>

#define BB   64
#define TT   512
#define KIN  256
#define HH   512
#define NBLK 64      // j-slices (8 columns of H each)
#define NJ   8
#define NW   4       // waves per block, each owns a K-quarter

typedef short bf16x8 __attribute__((ext_vector_type(8)));
typedef float f32x4  __attribute__((ext_vector_type(4)));

union U16x8 { unsigned short s[8]; bf16x8 v; };
union FU    { float f; unsigned u; };

__device__ __forceinline__ unsigned short f2bf(float f){
  FU v; v.f = f;
  unsigned r = v.u + 0x7fffu + ((v.u >> 16) & 1u);   // round-to-nearest-even
  return (unsigned short)(r >> 16);
}
__device__ __forceinline__ float bf2f(unsigned short s){
  FU v; v.u = ((unsigned)s) << 16; return v.f;
}
__device__ __forceinline__ bf16x8 zfrag(){
  U16x8 z;
  #pragma unroll
  for(int i=0;i<8;i++) z.s[i]=0;
  return z.v;
}
// 8 consecutive f32 -> split bf16 hi/lo fragments
__device__ __forceinline__ void split8(const float* p, bf16x8& hi, bf16x8& lo){
  float4 a = ((const float4*)p)[0];
  float4 b = ((const float4*)p)[1];
  float f[8] = {a.x,a.y,a.z,a.w,b.x,b.y,b.z,b.w};
  U16x8 h,l;
  #pragma unroll
  for(int i=0;i<8;i++){
    unsigned short hb = f2bf(f[i]);
    l.s[i] = f2bf(f[i] - bf2f(hb));
    h.s[i] = hb;
  }
  hi = h.v; lo = l.v;
}
// 8 packed u32 (bf16hi|bf16lo) via 4 agent-scope 64-bit atomic loads -> fragments
__device__ __forceinline__ void unpack8_a(const unsigned* p, bf16x8& hi, bf16x8& lo){
  const unsigned long long* q = (const unsigned long long*)p;
  unsigned long long d[4];
  #pragma unroll
  for(int i=0;i<4;i++)
    d[i] = __hip_atomic_load(q + i, __ATOMIC_RELAXED, __HIP_MEMORY_SCOPE_AGENT);
  U16x8 h,l;
  #pragma unroll
  for(int i=0;i<4;i++){
    unsigned w0 = (unsigned)d[i], w1 = (unsigned)(d[i] >> 32);
    h.s[2*i]   = (unsigned short)(w0 >> 16);  l.s[2*i]   = (unsigned short)(w0 & 0xffffu);
    h.s[2*i+1] = (unsigned short)(w1 >> 16);  l.s[2*i+1] = (unsigned short)(w1 & 0xffffu);
  }
  hi = h.v; lo = l.v;
}

#define MFMA __builtin_amdgcn_mfma_f32_16x16x32_bf16

__global__ __launch_bounds__(256, 1) void gru_scan(
    const float* __restrict__ x,  const float* __restrict__ Wm,
    const float* __restrict__ bW, const float* __restrict__ Um,
    const float* __restrict__ bU, float* __restrict__ out,
    unsigned* __restrict__ hbuf,  unsigned* __restrict__ cnt)
{
  __shared__ f32x4 red[NW][4][2][64];   // [writer-wave][Mt][Nt][lane] = 32 KB

  const int tid  = threadIdx.x;
  const int w    = tid >> 6;        // wave id = K-quarter
  const int lane = tid & 63;
  const int col  = lane & 15;       // N-index within 16x16 tile
  const int lg   = lane >> 4;       // k-group / M-subgroup
  const int j0   = blockIdx.x * NJ;

  // ---- persistent B fragments (U and W slices, split bf16, in registers) ----
  bf16x8 BUhi[2][4], BUlo[2][4], BWhi[2][2], BWlo[2][2];
  #pragma unroll
  for(int nt=0; nt<2; nt++){
    int rl    = nt*16 + col;          // local row 0..31 (24 valid)
    int valid = rl < 24;
    int g     = rl >> 3, jj = rl & 7;
    int grow  = g*HH + j0 + jj;       // row in [3H]
    #pragma unroll
    for(int ks=0; ks<4; ks++){
      int kb = w*128 + ks*32 + lg*8;
      if(valid) split8(Um + (size_t)grow*HH + kb, BUhi[nt][ks], BUlo[nt][ks]);
      else { BUhi[nt][ks]=zfrag(); BUlo[nt][ks]=zfrag(); }
    }
    #pragma unroll
    for(int ks=0; ks<2; ks++){
      int kb = w*64 + ks*32 + lg*8;
      if(valid) split8(Wm + (size_t)grow*KIN + kb, BWhi[nt][ks], BWlo[nt][ks]);
      else { BWhi[nt][ks]=zfrag(); BWlo[nt][ks]=zfrag(); }
    }
  }

  // ---- biases for this lane's gate rows ----
  float bsum0, bwn, bun;
  {
    int r0 = (col < 8) ? (j0 + col) : (HH + j0 + col - 8); // r-row or u-row
    bsum0 = bW[r0] + bU[r0];
    int rn = 2*HH + j0 + (col & 7);                        // n-row
    bwn = bW[rn]; bun = bU[rn];
  }

  float hreg[4] = {0.f,0.f,0.f,0.f};   // exact f32 h for this lane's (4 b, 1 j)
  unsigned bar = 0;

  for(int t=0; t<TT; t++){
    // ======== input projection xg for this timestep (K-quarter partials) ========
    f32x4 Cx[4][2];
    #pragma unroll
    for(int mt=0;mt<4;mt++){ Cx[mt][0]=(f32x4){0,0,0,0}; Cx[mt][1]=(f32x4){0,0,0,0}; }
    #pragma unroll
    for(int mt=0; mt<4; mt++){
      int b = mt*16 + col;
      #pragma unroll
      for(int ks=0; ks<2; ks++){
        int kb = w*64 + ks*32 + lg*8;
        bf16x8 ah, al; split8(x + ((size_t)b*TT + t)*KIN + kb, ah, al);
        #pragma unroll
        for(int nt=0; nt<2; nt++){
          Cx[mt][nt] = MFMA(ah, BWhi[nt][ks], Cx[mt][nt], 0,0,0);
          Cx[mt][nt] = MFMA(ah, BWlo[nt][ks], Cx[mt][nt], 0,0,0);
          Cx[mt][nt] = MFMA(al, BWhi[nt][ks], Cx[mt][nt], 0,0,0);
        }
      }
    }
    // reduce xg across the 4 K-quarter waves; wave w keeps Mt=w
    #pragma unroll
    for(int mt=0;mt<4;mt++)
      #pragma unroll
      for(int nt=0;nt<2;nt++)
        red[w][mt][nt][lane] = Cx[mt][nt];
    __syncthreads();
    f32x4 xgf[2];
    #pragma unroll
    for(int nt=0; nt<2; nt++){
      f32x4 s = Cx[w][nt];
      #pragma unroll
      for(int w2=0; w2<NW; w2++) if(w2 != w) s += red[w2][w][nt][lane];
      xgf[nt] = s;
    }
    __syncthreads();   // red reused below

    // ======== two GRU cells sharing this xg ========
    for(int l=0; l<2; l++){
      int c = 2*t + l;
      const unsigned* hb = hbuf + (size_t)(c & 1)       * (BB*HH);
      unsigned*       hw = hbuf + (size_t)((c & 1) ^ 1) * (BB*HH);

      f32x4 Ch[4][2];
      #pragma unroll
      for(int mt=0;mt<4;mt++){ Ch[mt][0]=(f32x4){0,0,0,0}; Ch[mt][1]=(f32x4){0,0,0,0}; }
      #pragma unroll
      for(int mt=0; mt<4; mt++){
        int b = mt*16 + col;
        #pragma unroll
        for(int ks=0; ks<4; ks++){
          int kb = w*128 + ks*32 + lg*8;
          bf16x8 ah, al; unpack8_a(hb + (size_t)b*HH + kb, ah, al);
          #pragma unroll
          for(int nt=0; nt<2; nt++){
            Ch[mt][nt] = MFMA(ah, BUhi[nt][ks], Ch[mt][nt], 0,0,0);
            Ch[mt][nt] = MFMA(ah, BUlo[nt][ks], Ch[mt][nt], 0,0,0);
            Ch[mt][nt] = MFMA(al, BUhi[nt][ks], Ch[mt][nt], 0,0,0);
          }
        }
      }
      #pragma unroll
      for(int mt=0;mt<4;mt++)
        #pragma unroll
        for(int nt=0;nt<2;nt++)
          red[w][mt][nt][lane] = Ch[mt][nt];
      __syncthreads();
      f32x4 hgf[2];
      #pragma unroll
      for(int nt=0; nt<2; nt++){
        f32x4 s = Ch[w][nt];
        #pragma unroll
        for(int w2=0; w2<NW; w2++) if(w2 != w) s += red[w2][w][nt][lane];
        hgf[nt] = s;
      }

      // ---- gates (wave w owns b in [w*16, w*16+16), lane col<8 owns j=j0+col) ----
      float p0[4], p0s[4];
      #pragma unroll
      for(int r=0;r<4;r++) p0[r] = xgf[0][r] + hgf[0][r] + bsum0;
      #pragma unroll
      for(int r=0;r<4;r++) p0s[r] = __shfl_xor(p0[r], 8, 64);  // swap r<->u lanes
      if(col < 8){
        #pragma unroll
        for(int r=0;r<4;r++){
          int b = w*16 + lg*4 + r;
          float rg = 1.f/(1.f + expf(-p0[r]));
          float ug = 1.f/(1.f + expf(-p0s[r]));
          float hn = hgf[1][r] + bun;
          float nn = tanhf(xgf[1][r] + bwn + rg*hn);
          float hnew = ug*hreg[r] + (1.f - ug)*nn;
          hreg[r] = hnew;
          unsigned short h16 = f2bf(hnew);
          unsigned short l16 = f2bf(hnew - bf2f(h16));
          __hip_atomic_store(&hw[(size_t)b*HH + j0 + col],
                             ((unsigned)h16 << 16) | (unsigned)l16,
                             __ATOMIC_RELAXED, __HIP_MEMORY_SCOPE_AGENT);
          out[((size_t)c*BB + b)*HH + j0 + col] = hnew;
        }
      }

      // ---- grid barrier: syncthreads drains stores (vmcnt), then release add ----
      bar++;
      __syncthreads();
      if(tid == 0){
        __hip_atomic_fetch_add(cnt, 1u, __ATOMIC_RELEASE, __HIP_MEMORY_SCOPE_AGENT);
        unsigned target = (unsigned)NBLK * bar;
        while(__hip_atomic_load(cnt, __ATOMIC_ACQUIRE, __HIP_MEMORY_SCOPE_AGENT) < target)
          __builtin_amdgcn_s_sleep(1);
      }
      __syncthreads();
    }
  }
}

extern "C" void kernel_launch(void* const* d_in, const int* in_sizes, int n_in,
                              void* d_out, int out_size, void* d_ws, size_t ws_size,
                              hipStream_t stream) {
  const float* x  = (const float*)d_in[0];
  const float* Wm = (const float*)d_in[1];
  const float* bW = (const float*)d_in[2];
  const float* Um = (const float*)d_in[3];
  const float* bU = (const float*)d_in[4];
  float* out = (float*)d_out;

  // ws layout: hbuf[2][64][512] u32 (256 KB) + counter
  unsigned* hbuf = (unsigned*)d_ws;
  unsigned* cnt  = (unsigned*)((char*)d_ws + 2*BB*HH*sizeof(unsigned));
  (void)hipMemsetAsync(d_ws, 0, 2*BB*HH*sizeof(unsigned) + 256, stream);

  gru_scan<<<NBLK, 256, 0, stream>>>(x, Wm, bW, Um, bU, out, hbuf, cnt);
}

// Round 4
// 14273.790 us; speedup vs baseline: 1.2061x; 1.2061x over previous
//
#include <hip/hip_runtime.h>
#include <stdint.h>

#define BB   64
#define TT   512
#define KIN  256
#define HH   512
#define NBLK 64      // j-slices (8 columns of H each)
#define NJ   8
#define NW   4       // waves per block, each owns a K-quarter

typedef short bf16x8 __attribute__((ext_vector_type(8)));
typedef float f32x4  __attribute__((ext_vector_type(4)));

union U16x8 { unsigned short s[8]; bf16x8 v; };
union FU    { float f; unsigned u; };

__device__ __forceinline__ unsigned short f2bf(float f){
  FU v; v.f = f;
  unsigned r = v.u + 0x7fffu + ((v.u >> 16) & 1u);   // round-to-nearest-even
  return (unsigned short)(r >> 16);
}
__device__ __forceinline__ float bf2f(unsigned short s){
  FU v; v.u = ((unsigned)s) << 16; return v.f;
}
__device__ __forceinline__ bf16x8 zfrag(){
  U16x8 z;
  #pragma unroll
  for(int i=0;i<8;i++) z.s[i]=0;
  return z.v;
}
// 8 consecutive f32 -> split bf16 hi/lo fragments
__device__ __forceinline__ void split8(const float* p, bf16x8& hi, bf16x8& lo){
  float4 a = ((const float4*)p)[0];
  float4 b = ((const float4*)p)[1];
  float f[8] = {a.x,a.y,a.z,a.w,b.x,b.y,b.z,b.w};
  U16x8 h,l;
  #pragma unroll
  for(int i=0;i<8;i++){
    unsigned short hb = f2bf(f[i]);
    l.s[i] = f2bf(f[i] - bf2f(hb));
    h.s[i] = hb;
  }
  hi = h.v; lo = l.v;
}
// 8 packed u32 (bf16hi|bf16lo) via 4 agent-scope 64-bit relaxed loads (LLC-direct)
__device__ __forceinline__ void unpack8_a(const unsigned* p, bf16x8& hi, bf16x8& lo){
  const unsigned long long* q = (const unsigned long long*)p;
  unsigned long long d[4];
  #pragma unroll
  for(int i=0;i<4;i++)
    d[i] = __hip_atomic_load(q + i, __ATOMIC_RELAXED, __HIP_MEMORY_SCOPE_AGENT);
  U16x8 h,l;
  #pragma unroll
  for(int i=0;i<4;i++){
    unsigned w0 = (unsigned)d[i], w1 = (unsigned)(d[i] >> 32);
    h.s[2*i]   = (unsigned short)(w0 >> 16);  l.s[2*i]   = (unsigned short)(w0 & 0xffffu);
    h.s[2*i+1] = (unsigned short)(w1 >> 16);  l.s[2*i+1] = (unsigned short)(w1 & 0xffffu);
  }
  hi = h.v; lo = l.v;
}

#define MFMA __builtin_amdgcn_mfma_f32_16x16x32_bf16

__global__ __launch_bounds__(256, 1) void gru_scan(
    const float* __restrict__ x,  const float* __restrict__ Wm,
    const float* __restrict__ bW, const float* __restrict__ Um,
    const float* __restrict__ bU, float* __restrict__ out,
    unsigned* __restrict__ hbuf,  unsigned* __restrict__ flags)
{
  __shared__ f32x4 red [NW][4][2][64];   // h-gate reduce (32 KB)
  __shared__ f32x4 red2[NW][4][2][64];   // xg reduce     (32 KB)

  const int tid  = threadIdx.x;
  const int w    = tid >> 6;        // wave id = K-quarter
  const int lane = tid & 63;
  const int col  = lane & 15;       // N-index within 16x16 tile
  const int lg   = lane >> 4;       // k-group / M-subgroup
  const int j0   = blockIdx.x * NJ;
  const int bid  = blockIdx.x;

  // ---- persistent B fragments (U and W slices, split bf16, in registers) ----
  bf16x8 BUhi[2][4], BUlo[2][4], BWhi[2][2], BWlo[2][2];
  #pragma unroll
  for(int nt=0; nt<2; nt++){
    int rl    = nt*16 + col;          // local row 0..31 (24 valid)
    int valid = rl < 24;
    int g     = rl >> 3, jj = rl & 7;
    int grow  = g*HH + j0 + jj;       // row in [3H]
    #pragma unroll
    for(int ks=0; ks<4; ks++){
      int kb = w*128 + ks*32 + lg*8;
      if(valid) split8(Um + (size_t)grow*HH + kb, BUhi[nt][ks], BUlo[nt][ks]);
      else { BUhi[nt][ks]=zfrag(); BUlo[nt][ks]=zfrag(); }
    }
    #pragma unroll
    for(int ks=0; ks<2; ks++){
      int kb = w*64 + ks*32 + lg*8;
      if(valid) split8(Wm + (size_t)grow*KIN + kb, BWhi[nt][ks], BWlo[nt][ks]);
      else { BWhi[nt][ks]=zfrag(); BWlo[nt][ks]=zfrag(); }
    }
  }

  // ---- biases for this lane's gate rows ----
  float bsum0, bwn, bun;
  {
    int r0 = (col < 8) ? (j0 + col) : (HH + j0 + col - 8); // r-row or u-row
    bsum0 = bW[r0] + bU[r0];
    int rn = 2*HH + j0 + (col & 7);                        // n-row
    bwn = bW[rn]; bun = bU[rn];
  }

  float hreg[4] = {0.f,0.f,0.f,0.f};   // exact f32 h for this lane's (4 b, 1 j)
  unsigned bar = 0;

  // ---- xg partial-compute + cross-wave reduce (uses red2) ----
  auto compute_xg = [&](int tt, f32x4 (&dst)[2]){
    f32x4 Cx[4][2];
    #pragma unroll
    for(int mt=0;mt<4;mt++){ Cx[mt][0]=(f32x4){0,0,0,0}; Cx[mt][1]=(f32x4){0,0,0,0}; }
    #pragma unroll
    for(int mt=0; mt<4; mt++){
      int b = mt*16 + col;
      #pragma unroll
      for(int ks=0; ks<2; ks++){
        int kb = w*64 + ks*32 + lg*8;
        bf16x8 ah, al; split8(x + ((size_t)b*TT + tt)*KIN + kb, ah, al);
        #pragma unroll
        for(int nt=0; nt<2; nt++){
          Cx[mt][nt] = MFMA(ah, BWhi[nt][ks], Cx[mt][nt], 0,0,0);
          Cx[mt][nt] = MFMA(ah, BWlo[nt][ks], Cx[mt][nt], 0,0,0);
          Cx[mt][nt] = MFMA(al, BWhi[nt][ks], Cx[mt][nt], 0,0,0);
        }
      }
    }
    #pragma unroll
    for(int mt=0;mt<4;mt++)
      #pragma unroll
      for(int nt=0;nt<2;nt++)
        red2[w][mt][nt][lane] = Cx[mt][nt];
    __syncthreads();
    #pragma unroll
    for(int nt=0; nt<2; nt++){
      f32x4 s = Cx[w][nt];
      #pragma unroll
      for(int w2=0; w2<NW; w2++) if(w2 != w) s += red2[w2][w][nt][lane];
      dst[nt] = s;
    }
  };

  // ---- one GRU cell: h-matmul, gates, h-store, arrive(flag) ----
  auto run_cell = [&](const unsigned* hb, unsigned* hw, const f32x4 (&xgf)[2],
                      float (&on)[4]){
    f32x4 Ch[4][2];
    #pragma unroll
    for(int mt=0;mt<4;mt++){ Ch[mt][0]=(f32x4){0,0,0,0}; Ch[mt][1]=(f32x4){0,0,0,0}; }
    #pragma unroll
    for(int mt=0; mt<4; mt++){
      int b = mt*16 + col;
      #pragma unroll
      for(int ks=0; ks<4; ks++){
        int kb = w*128 + ks*32 + lg*8;
        bf16x8 ah, al; unpack8_a(hb + (size_t)b*HH + kb, ah, al);
        #pragma unroll
        for(int nt=0; nt<2; nt++){
          Ch[mt][nt] = MFMA(ah, BUhi[nt][ks], Ch[mt][nt], 0,0,0);
          Ch[mt][nt] = MFMA(ah, BUlo[nt][ks], Ch[mt][nt], 0,0,0);
          Ch[mt][nt] = MFMA(al, BUhi[nt][ks], Ch[mt][nt], 0,0,0);
        }
      }
    }
    #pragma unroll
    for(int mt=0;mt<4;mt++)
      #pragma unroll
      for(int nt=0;nt<2;nt++)
        red[w][mt][nt][lane] = Ch[mt][nt];
    __syncthreads();
    f32x4 hgf[2];
    #pragma unroll
    for(int nt=0; nt<2; nt++){
      f32x4 s = Ch[w][nt];
      #pragma unroll
      for(int w2=0; w2<NW; w2++) if(w2 != w) s += red[w2][w][nt][lane];
      hgf[nt] = s;
    }
    // gates (wave w owns b in [w*16, w*16+16), lane col<8 owns j=j0+col)
    float p0[4], p0s[4];
    #pragma unroll
    for(int r=0;r<4;r++) p0[r] = xgf[0][r] + hgf[0][r] + bsum0;
    #pragma unroll
    for(int r=0;r<4;r++) p0s[r] = __shfl_xor(p0[r], 8, 64);  // swap r<->u lanes
    if(col < 8){
      #pragma unroll
      for(int r=0;r<4;r++){
        int b = w*16 + lg*4 + r;
        float rg = 1.f/(1.f + __expf(-p0[r]));
        float ug = 1.f/(1.f + __expf(-p0s[r]));
        float hn = hgf[1][r] + bun;
        float nn = tanhf(xgf[1][r] + bwn + rg*hn);
        float hnew = ug*hreg[r] + (1.f - ug)*nn;
        hreg[r] = hnew;
        on[r]   = hnew;
        unsigned short h16 = f2bf(hnew);
        unsigned short l16 = f2bf(hnew - bf2f(h16));
        __hip_atomic_store(&hw[(size_t)b*HH + j0 + col],
                           ((unsigned)h16 << 16) | (unsigned)l16,
                           __ATOMIC_RELAXED, __HIP_MEMORY_SCOPE_AGENT);
      }
    }
    bar++;
    __syncthreads();   // compiler emits vmcnt(0) drain before s_barrier -> all
                       // waves' write-through h-stores are at LLC when released
    if(tid == 0)
      __hip_atomic_store(&flags[bid], bar, __ATOMIC_RELAXED, __HIP_MEMORY_SCOPE_AGENT);
  };

  // ---- relaxed all-wave barrier wait: lane i watches flags[i] ----
  auto poll = [&](){
    unsigned tgt = bar;
    while(true){
      unsigned f = __hip_atomic_load(&flags[lane], __ATOMIC_RELAXED, __HIP_MEMORY_SCOPE_AGENT);
      if(__all((int)(f >= tgt))) break;
      __builtin_amdgcn_s_sleep(1);
    }
    __builtin_amdgcn_sched_barrier(0);
    asm volatile("" ::: "memory");
  };

  f32x4 xgf[2], xgn[2];
  compute_xg(0, xgf);

  float on0[4], on1[4];
  for(int t=0; t<TT; t++){
    // ---- layer 0: read buf0, write buf1 ----
    run_cell(hbuf, hbuf + (size_t)BB*HH, xgf, on0);
    // overlap window: deferred out-stores + next timestep's xg
    if(col < 8){
      #pragma unroll
      for(int r=0;r<4;r++){
        int b = w*16 + lg*4 + r;
        out[((size_t)(2*t)*BB + b)*HH + j0 + col] = on0[r];
      }
    }
    if(t+1 < TT) compute_xg(t+1, xgn);
    poll();
    // ---- layer 1: read buf1, write buf0 ----
    run_cell(hbuf + (size_t)BB*HH, hbuf, xgf, on1);
    if(col < 8){
      #pragma unroll
      for(int r=0;r<4;r++){
        int b = w*16 + lg*4 + r;
        out[((size_t)(2*t+1)*BB + b)*HH + j0 + col] = on1[r];
      }
    }
    poll();
    xgf[0] = xgn[0]; xgf[1] = xgn[1];
  }
}

extern "C" void kernel_launch(void* const* d_in, const int* in_sizes, int n_in,
                              void* d_out, int out_size, void* d_ws, size_t ws_size,
                              hipStream_t stream) {
  const float* x  = (const float*)d_in[0];
  const float* Wm = (const float*)d_in[1];
  const float* bW = (const float*)d_in[2];
  const float* Um = (const float*)d_in[3];
  const float* bU = (const float*)d_in[4];
  float* out = (float*)d_out;

  // ws layout: hbuf[2][64][512] u32 (256 KB) + flags[64] u32
  unsigned* hbuf  = (unsigned*)d_ws;
  unsigned* flags = (unsigned*)((char*)d_ws + 2*BB*HH*sizeof(unsigned));
  (void)hipMemsetAsync(d_ws, 0, 2*BB*HH*sizeof(unsigned) + 256, stream);

  gru_scan<<<NBLK, 256, 0, stream>>>(x, Wm, bW, Um, bU, out, hbuf, flags);
}

// Round 5
// 10310.039 us; speedup vs baseline: 1.6698x; 1.3845x over previous
//
#include <hip/hip_runtime.h>
#include <stdint.h>

#define BB   64
#define TT   512
#define KIN  256
#define HH   512
#define NBLK 64      // j-slices (8 columns of H each)
#define NJ   8

typedef short bf16x8 __attribute__((ext_vector_type(8)));
typedef float f32x4  __attribute__((ext_vector_type(4)));
typedef unsigned long long u64;

union U16x8 { unsigned short s[8]; bf16x8 v; };
union FU    { float f; unsigned u; };

__device__ __forceinline__ unsigned short f2bf(float f){
  FU v; v.f = f;
  unsigned r = v.u + 0x7fffu + ((v.u >> 16) & 1u);   // RNE
  return (unsigned short)(r >> 16);
}
__device__ __forceinline__ float bf2f(unsigned short s){
  FU v; v.u = ((unsigned)s) << 16; return v.f;
}
__device__ __forceinline__ bf16x8 zfrag(){
  U16x8 z;
  #pragma unroll
  for(int i=0;i<8;i++) z.s[i]=0;
  return z.v;
}
// 8 consecutive f32 -> split bf16 hi/lo fragments
__device__ __forceinline__ void split8(const float* p, bf16x8& hi, bf16x8& lo){
  float4 a = ((const float4*)p)[0];
  float4 b = ((const float4*)p)[1];
  float f[8] = {a.x,a.y,a.z,a.w,b.x,b.y,b.z,b.w};
  U16x8 h,l;
  #pragma unroll
  for(int i=0;i<8;i++){
    unsigned short hb = f2bf(f[i]);
    l.s[i] = f2bf(f[i] - bf2f(hb));
    h.s[i] = hb;
  }
  hi = h.v; lo = l.v;
}
// 4 u64 (each 2 packed bf16hi|lo words) -> hi/lo fragments
__device__ __forceinline__ void unpackpair(const u64* d, bf16x8& hi, bf16x8& lo){
  U16x8 h,l;
  #pragma unroll
  for(int i=0;i<4;i++){
    unsigned w0 = (unsigned)d[i], w1 = (unsigned)(d[i] >> 32);
    h.s[2*i]   = (unsigned short)(w0 >> 16);  l.s[2*i]   = (unsigned short)(w0 & 0xffffu);
    h.s[2*i+1] = (unsigned short)(w1 >> 16);  l.s[2*i+1] = (unsigned short)(w1 & 0xffffu);
  }
  hi = h.v; lo = l.v;
}

#define MFMA __builtin_amdgcn_mfma_f32_16x16x32_bf16

__global__ __launch_bounds__(512, 2) void gru_scan(
    const float* __restrict__ x,  const float* __restrict__ Wm,
    const float* __restrict__ bW, const float* __restrict__ Um,
    const float* __restrict__ bU, float* __restrict__ out,
    unsigned* __restrict__ hbuf,  unsigned* __restrict__ flags)
{
  __shared__ f32x4 red [4][4][2][64];   // [q][mt][nt][lane] h-gate reduce (32 KB)
  __shared__ f32x4 red2[4][4][2][64];   // xg reduce (32 KB)

  const int tid  = threadIdx.x;
  const int u    = tid >> 6;        // wave 0..7
  const int q    = u >> 1;          // k-quarter
  const int m2   = u & 1;           // mt-pair: this wave computes mt in {2*m2, 2*m2+1}
  const int lane = tid & 63;
  const int col  = lane & 15;
  const int lg   = lane >> 4;
  const int j0   = blockIdx.x * NJ;
  const int bid  = blockIdx.x;

  // ---- persistent U/W fragments for k-quarter q (split bf16, registers) ----
  bf16x8 BUhi[2][4], BUlo[2][4], BWhi[2][2], BWlo[2][2];
  #pragma unroll
  for(int nt=0; nt<2; nt++){
    int rl    = nt*16 + col;          // local row 0..31 (24 valid)
    int valid = rl < 24;
    int g     = rl >> 3, jj = rl & 7;
    int grow  = g*HH + j0 + jj;       // row in [3H]
    #pragma unroll
    for(int ks=0; ks<4; ks++){
      int kb = q*128 + ks*32 + lg*8;
      if(valid) split8(Um + (size_t)grow*HH + kb, BUhi[nt][ks], BUlo[nt][ks]);
      else { BUhi[nt][ks]=zfrag(); BUlo[nt][ks]=zfrag(); }
    }
    #pragma unroll
    for(int ks=0; ks<2; ks++){
      int kb = q*64 + ks*32 + lg*8;
      if(valid) split8(Wm + (size_t)grow*KIN + kb, BWhi[nt][ks], BWlo[nt][ks]);
      else { BWhi[nt][ks]=zfrag(); BWlo[nt][ks]=zfrag(); }
    }
  }

  // ---- biases for this lane's gate rows (used by gate waves u<4) ----
  float bsum0, bwn, bun;
  {
    int r0 = (col < 8) ? (j0 + col) : (HH + j0 + col - 8);
    bsum0 = bW[r0] + bU[r0];
    int rn = 2*HH + j0 + (col & 7);
    bwn = bW[rn]; bun = bU[rn];
  }

  float hreg[4] = {0.f,0.f,0.f,0.f};
  unsigned bar = 0;

  // ---- xg partials + cross-wave reduce (red2); gate waves get sums ----
  auto compute_xg = [&](int tt, f32x4 (&dst)[2]){
    f32x4 Cx[2][2];
    #pragma unroll
    for(int mi=0;mi<2;mi++){ Cx[mi][0]=(f32x4){0,0,0,0}; Cx[mi][1]=(f32x4){0,0,0,0}; }
    #pragma unroll
    for(int mi=0; mi<2; mi++){
      int mt = 2*m2 + mi, b = mt*16 + col;
      #pragma unroll
      for(int ks=0; ks<2; ks++){
        int kb = q*64 + ks*32 + lg*8;
        bf16x8 ah, al; split8(x + ((size_t)b*TT + tt)*KIN + kb, ah, al);
        #pragma unroll
        for(int nt=0; nt<2; nt++){
          Cx[mi][nt] = MFMA(ah, BWhi[nt][ks], Cx[mi][nt], 0,0,0);
          Cx[mi][nt] = MFMA(ah, BWlo[nt][ks], Cx[mi][nt], 0,0,0);
          Cx[mi][nt] = MFMA(al, BWhi[nt][ks], Cx[mi][nt], 0,0,0);
        }
      }
    }
    #pragma unroll
    for(int mi=0;mi<2;mi++)
      #pragma unroll
      for(int nt=0;nt<2;nt++)
        red2[q][2*m2+mi][nt][lane] = Cx[mi][nt];
    __syncthreads();
    if(u < 4){
      #pragma unroll
      for(int nt=0; nt<2; nt++)
        dst[nt] = red2[0][u][nt][lane] + red2[1][u][nt][lane]
                + red2[2][u][nt][lane] + red2[3][u][nt][lane];
    }
  };

  // ---- one GRU cell ----
  auto run_cell = [&](const unsigned* hb, unsigned* hw, const f32x4 (&xgf)[2],
                      float (&on)[4]){
    // issue ALL 32 h-loads upfront (one latency exposure)
    u64 hv[2][16];
    #pragma unroll
    for(int mi=0; mi<2; mi++){
      int mt = 2*m2 + mi, b = mt*16 + col;
      const u64* base = (const u64*)hb + (size_t)b*(HH/2) + q*64 + lg*4;
      #pragma unroll
      for(int ks=0; ks<4; ks++)
        #pragma unroll
        for(int i=0; i<4; i++)
          hv[mi][ks*4+i] = __hip_atomic_load(base + ks*16 + i,
                             __ATOMIC_RELAXED, __HIP_MEMORY_SCOPE_AGENT);
    }
    f32x4 Ch[2][2];
    #pragma unroll
    for(int mi=0;mi<2;mi++){ Ch[mi][0]=(f32x4){0,0,0,0}; Ch[mi][1]=(f32x4){0,0,0,0}; }
    #pragma unroll
    for(int mi=0; mi<2; mi++){
      #pragma unroll
      for(int ks=0; ks<4; ks++){
        bf16x8 ah, al; unpackpair(&hv[mi][ks*4], ah, al);
        #pragma unroll
        for(int nt=0; nt<2; nt++){
          Ch[mi][nt] = MFMA(ah, BUhi[nt][ks], Ch[mi][nt], 0,0,0);
          Ch[mi][nt] = MFMA(ah, BUlo[nt][ks], Ch[mi][nt], 0,0,0);
          Ch[mi][nt] = MFMA(al, BUhi[nt][ks], Ch[mi][nt], 0,0,0);
        }
      }
    }
    #pragma unroll
    for(int mi=0;mi<2;mi++)
      #pragma unroll
      for(int nt=0;nt<2;nt++)
        red[q][2*m2+mi][nt][lane] = Ch[mi][nt];
    __syncthreads();
    if(u < 4){
      const int w = u;
      f32x4 hgf[2];
      #pragma unroll
      for(int nt=0; nt<2; nt++)
        hgf[nt] = red[0][w][nt][lane] + red[1][w][nt][lane]
                + red[2][w][nt][lane] + red[3][w][nt][lane];
      float p0[4], p0s[4];
      #pragma unroll
      for(int r=0;r<4;r++) p0[r] = xgf[0][r] + hgf[0][r] + bsum0;
      #pragma unroll
      for(int r=0;r<4;r++) p0s[r] = __shfl_xor(p0[r], 8, 64);
      if(col < 8){
        #pragma unroll
        for(int r=0;r<4;r++){
          int b = w*16 + lg*4 + r;
          float rg = __builtin_amdgcn_rcpf(1.f + __expf(-p0[r]));
          float ug = __builtin_amdgcn_rcpf(1.f + __expf(-p0s[r]));
          float hn = hgf[1][r] + bun;
          float z  = xgf[1][r] + bwn + rg*hn;
          z = fminf(fmaxf(z, -15.f), 15.f);
          float e  = __expf(2.f*z);
          float nn = (e - 1.f) * __builtin_amdgcn_rcpf(e + 1.f);   // tanh(z)
          float hnew = ug*hreg[r] + (1.f - ug)*nn;
          hreg[r] = hnew;
          on[r]   = hnew;
          unsigned short h16 = f2bf(hnew);
          unsigned short l16 = f2bf(hnew - bf2f(h16));
          __hip_atomic_store(&hw[(size_t)b*HH + j0 + col],
                             ((unsigned)h16 << 16) | (unsigned)l16,
                             __ATOMIC_RELAXED, __HIP_MEMORY_SCOPE_AGENT);
        }
      }
    }
    bar++;
    __syncthreads();   // per-wave vmcnt(0) drain: all h-stores at LLC before flag
    if(tid == 0)
      __hip_atomic_store(&flags[bid], bar, __ATOMIC_RELAXED, __HIP_MEMORY_SCOPE_AGENT);
  };

  // ---- relaxed barrier wait: lane i watches flags[i] ----
  auto poll = [&](){
    unsigned tgt = bar;
    while(true){
      unsigned f = __hip_atomic_load(&flags[lane], __ATOMIC_RELAXED, __HIP_MEMORY_SCOPE_AGENT);
      if(__all((int)(f >= tgt))) break;
      __builtin_amdgcn_s_sleep(1);
    }
    __builtin_amdgcn_sched_barrier(0);
    asm volatile("" ::: "memory");
  };

  f32x4 xgf[2] = {(f32x4){0,0,0,0},(f32x4){0,0,0,0}};
  f32x4 xgn[2] = {(f32x4){0,0,0,0},(f32x4){0,0,0,0}};
  float on0[4] = {0,0,0,0}, on1[4] = {0,0,0,0};
  compute_xg(0, xgf);

  for(int t=0; t<TT; t++){
    // ---- layer 0: read buf0, write buf1 ----
    run_cell(hbuf, hbuf + (size_t)BB*HH, xgf, on0);
    if(u < 4 && col < 8){
      #pragma unroll
      for(int r=0;r<4;r++){
        int b = u*16 + lg*4 + r;
        out[((size_t)(2*t)*BB + b)*HH + j0 + col] = on0[r];
      }
    }
    if(t+1 < TT) compute_xg(t+1, xgn);
    poll();
    // ---- layer 1: read buf1, write buf0 (same xg) ----
    run_cell(hbuf + (size_t)BB*HH, hbuf, xgf, on1);
    if(u < 4 && col < 8){
      #pragma unroll
      for(int r=0;r<4;r++){
        int b = u*16 + lg*4 + r;
        out[((size_t)(2*t+1)*BB + b)*HH + j0 + col] = on1[r];
      }
    }
    poll();
    xgf[0] = xgn[0]; xgf[1] = xgn[1];
  }
}

extern "C" void kernel_launch(void* const* d_in, const int* in_sizes, int n_in,
                              void* d_out, int out_size, void* d_ws, size_t ws_size,
                              hipStream_t stream) {
  const float* x  = (const float*)d_in[0];
  const float* Wm = (const float*)d_in[1];
  const float* bW = (const float*)d_in[2];
  const float* Um = (const float*)d_in[3];
  const float* bU = (const float*)d_in[4];
  float* out = (float*)d_out;

  // ws layout: hbuf[2][64][512] u32 (256 KB) + flags[64] u32
  unsigned* hbuf  = (unsigned*)d_ws;
  unsigned* flags = (unsigned*)((char*)d_ws + 2*BB*HH*sizeof(unsigned));
  (void)hipMemsetAsync(d_ws, 0, 2*BB*HH*sizeof(unsigned) + 256, stream);

  gru_scan<<<NBLK, 512, 0, stream>>>(x, Wm, bW, Um, bU, out, hbuf, flags);
}

// Round 6
// 7117.609 us; speedup vs baseline: 2.4188x; 1.4485x over previous
//
#include <hip/hip_runtime.h>
#include <stdint.h>

#define BB   64
#define TT   512
#define KIN  256
#define HH   512
#define NBLK 64      // j-slices (8 columns of H each)
#define NJ   8

typedef short bf16x8 __attribute__((ext_vector_type(8)));
typedef float f32x4  __attribute__((ext_vector_type(4)));
typedef unsigned long long u64;

union U16x8 { unsigned short s[8]; bf16x8 v; };
union FU    { float f; unsigned u; };

__device__ __forceinline__ unsigned short f2bf(float f){
  FU v; v.f = f;
  unsigned r = v.u + 0x7fffu + ((v.u >> 16) & 1u);   // RNE
  return (unsigned short)(r >> 16);
}
__device__ __forceinline__ float bf2f(unsigned short s){
  FU v; v.u = ((unsigned)s) << 16; return v.f;
}
__device__ __forceinline__ bf16x8 zfrag(){
  U16x8 z;
  #pragma unroll
  for(int i=0;i<8;i++) z.s[i]=0;
  return z.v;
}
// 8 consecutive f32 -> split bf16 hi/lo fragments
__device__ __forceinline__ void split8(const float* p, bf16x8& hi, bf16x8& lo){
  float4 a = ((const float4*)p)[0];
  float4 b = ((const float4*)p)[1];
  float f[8] = {a.x,a.y,a.z,a.w,b.x,b.y,b.z,b.w};
  U16x8 h,l;
  #pragma unroll
  for(int i=0;i<8;i++){
    unsigned short hb = f2bf(f[i]);
    l.s[i] = f2bf(f[i] - bf2f(hb));
    h.s[i] = hb;
  }
  hi = h.v; lo = l.v;
}
// two uint4 (8 packed u32 words, bf16hi|bf16lo) -> hi/lo fragments
__device__ __forceinline__ void unpackg(uint4 A, uint4 B, bf16x8& hi, bf16x8& lo){
  unsigned wv[8] = {A.x,A.y,A.z,A.w,B.x,B.y,B.z,B.w};
  U16x8 h,l;
  #pragma unroll
  for(int j=0;j<8;j++){
    h.s[j] = (unsigned short)(wv[j] >> 16);
    l.s[j] = (unsigned short)(wv[j] & 0xffffu);
  }
  hi = h.v; lo = l.v;
}

#define MFMA __builtin_amdgcn_mfma_f32_16x16x32_bf16

__global__ __launch_bounds__(512, 2) void gru_scan(
    const float* __restrict__ x,  const float* __restrict__ Wm,
    const float* __restrict__ bW, const float* __restrict__ Um,
    const float* __restrict__ bU, float* __restrict__ out,
    unsigned* __restrict__ hbuf,  unsigned* __restrict__ flags)
{
  __shared__ f32x4 red [4][4][2][64];   // [q][mt][nt][lane] h-gate reduce (32 KB)
  __shared__ f32x4 red2[4][4][2][64];   // xg reduce (32 KB)

  const int tid  = threadIdx.x;
  const int u    = tid >> 6;        // wave 0..7
  const int q    = u >> 1;          // k-quarter
  const int m2   = u & 1;           // mt-pair: this wave computes mt in {2*m2, 2*m2+1}
  const int lane = tid & 63;
  const int col  = lane & 15;
  const int lg   = lane >> 4;
  const int j0   = blockIdx.x * NJ;
  const int bid  = blockIdx.x;

  // ---- persistent U/W fragments for k-quarter q (split bf16, registers) ----
  bf16x8 BUhi[2][4], BUlo[2][4], BWhi[2][2], BWlo[2][2];
  #pragma unroll
  for(int nt=0; nt<2; nt++){
    int rl    = nt*16 + col;          // local row 0..31 (24 valid)
    int valid = rl < 24;
    int g     = rl >> 3, jj = rl & 7;
    int grow  = g*HH + j0 + jj;       // row in [3H]
    #pragma unroll
    for(int ks=0; ks<4; ks++){
      int kb = q*128 + ks*32 + lg*8;
      if(valid) split8(Um + (size_t)grow*HH + kb, BUhi[nt][ks], BUlo[nt][ks]);
      else { BUhi[nt][ks]=zfrag(); BUlo[nt][ks]=zfrag(); }
    }
    #pragma unroll
    for(int ks=0; ks<2; ks++){
      int kb = q*64 + ks*32 + lg*8;
      if(valid) split8(Wm + (size_t)grow*KIN + kb, BWhi[nt][ks], BWlo[nt][ks]);
      else { BWhi[nt][ks]=zfrag(); BWlo[nt][ks]=zfrag(); }
    }
  }

  // ---- biases for this lane's gate rows (used by gate waves u<4) ----
  float bsum0, bwn, bun;
  {
    int r0 = (col < 8) ? (j0 + col) : (HH + j0 + col - 8);
    bsum0 = bW[r0] + bU[r0];
    int rn = 2*HH + j0 + (col & 7);
    bwn = bW[rn]; bun = bU[rn];
  }

  float hreg[4] = {0.f,0.f,0.f,0.f};
  unsigned bar = 0;

  // ---- xg partials + cross-wave reduce (red2); gate waves get sums ----
  auto compute_xg = [&](int tt, f32x4 (&dst)[2]){
    f32x4 Cx[2][2];
    #pragma unroll
    for(int mi=0;mi<2;mi++){ Cx[mi][0]=(f32x4){0,0,0,0}; Cx[mi][1]=(f32x4){0,0,0,0}; }
    #pragma unroll
    for(int mi=0; mi<2; mi++){
      int mt = 2*m2 + mi, b = mt*16 + col;
      #pragma unroll
      for(int ks=0; ks<2; ks++){
        int kb = q*64 + ks*32 + lg*8;
        bf16x8 ah, al; split8(x + ((size_t)b*TT + tt)*KIN + kb, ah, al);
        #pragma unroll
        for(int nt=0; nt<2; nt++){
          Cx[mi][nt] = MFMA(ah, BWhi[nt][ks], Cx[mi][nt], 0,0,0);
          Cx[mi][nt] = MFMA(ah, BWlo[nt][ks], Cx[mi][nt], 0,0,0);
          Cx[mi][nt] = MFMA(al, BWhi[nt][ks], Cx[mi][nt], 0,0,0);
        }
      }
    }
    #pragma unroll
    for(int mi=0;mi<2;mi++)
      #pragma unroll
      for(int nt=0;nt<2;nt++)
        red2[q][2*m2+mi][nt][lane] = Cx[mi][nt];
    __syncthreads();
    if(u < 4){
      #pragma unroll
      for(int nt=0; nt<2; nt++)
        dst[nt] = red2[0][u][nt][lane] + red2[1][u][nt][lane]
                + red2[2][u][nt][lane] + red2[3][u][nt][lane];
    }
  };

  // ---- one GRU cell ----
  auto run_cell = [&](const unsigned* hb, unsigned* hw, const f32x4 (&xgf)[2],
                      float (&on)[4]){
    // pipelined coherent h-loads: 16 x dwordx4 sc1 (device-scope, L2-bypass),
    // ONE latency exposure. rule #18: manual vmcnt + sched_barrier after.
    int b0 = (2*m2+0)*16 + col, b1 = (2*m2+1)*16 + col;
    const void* a0 = (const char*)hb + ((size_t)b0*HH + q*128 + lg*8)*4;
    const void* a1 = (const char*)hb + ((size_t)b1*HH + q*128 + lg*8)*4;
    uint4 g00,g01,g02,g03,g04,g05,g06,g07;
    uint4 g10,g11,g12,g13,g14,g15,g16,g17;
    asm volatile(
      "global_load_dwordx4 %0, %16, off sc1\n\t"
      "global_load_dwordx4 %1, %16, off offset:16 sc1\n\t"
      "global_load_dwordx4 %2, %16, off offset:128 sc1\n\t"
      "global_load_dwordx4 %3, %16, off offset:144 sc1\n\t"
      "global_load_dwordx4 %4, %16, off offset:256 sc1\n\t"
      "global_load_dwordx4 %5, %16, off offset:272 sc1\n\t"
      "global_load_dwordx4 %6, %16, off offset:384 sc1\n\t"
      "global_load_dwordx4 %7, %16, off offset:400 sc1\n\t"
      "global_load_dwordx4 %8, %17, off sc1\n\t"
      "global_load_dwordx4 %9, %17, off offset:16 sc1\n\t"
      "global_load_dwordx4 %10, %17, off offset:128 sc1\n\t"
      "global_load_dwordx4 %11, %17, off offset:144 sc1\n\t"
      "global_load_dwordx4 %12, %17, off offset:256 sc1\n\t"
      "global_load_dwordx4 %13, %17, off offset:272 sc1\n\t"
      "global_load_dwordx4 %14, %17, off offset:384 sc1\n\t"
      "global_load_dwordx4 %15, %17, off offset:400 sc1"
      : "=&v"(g00),"=&v"(g01),"=&v"(g02),"=&v"(g03),
        "=&v"(g04),"=&v"(g05),"=&v"(g06),"=&v"(g07),
        "=&v"(g10),"=&v"(g11),"=&v"(g12),"=&v"(g13),
        "=&v"(g14),"=&v"(g15),"=&v"(g16),"=&v"(g17)
      : "v"(a0), "v"(a1)
      : "memory");
    asm volatile("s_waitcnt vmcnt(0)" ::: "memory");
    __builtin_amdgcn_sched_barrier(0);

    f32x4 Ch[2][2];
    #pragma unroll
    for(int mi=0;mi<2;mi++){ Ch[mi][0]=(f32x4){0,0,0,0}; Ch[mi][1]=(f32x4){0,0,0,0}; }
    {
      bf16x8 ah, al;
      // mi = 0
      unpackg(g00,g01,ah,al);
      #pragma unroll
      for(int nt=0;nt<2;nt++){ Ch[0][nt]=MFMA(ah,BUhi[nt][0],Ch[0][nt],0,0,0); Ch[0][nt]=MFMA(ah,BUlo[nt][0],Ch[0][nt],0,0,0); Ch[0][nt]=MFMA(al,BUhi[nt][0],Ch[0][nt],0,0,0); }
      unpackg(g02,g03,ah,al);
      #pragma unroll
      for(int nt=0;nt<2;nt++){ Ch[0][nt]=MFMA(ah,BUhi[nt][1],Ch[0][nt],0,0,0); Ch[0][nt]=MFMA(ah,BUlo[nt][1],Ch[0][nt],0,0,0); Ch[0][nt]=MFMA(al,BUhi[nt][1],Ch[0][nt],0,0,0); }
      unpackg(g04,g05,ah,al);
      #pragma unroll
      for(int nt=0;nt<2;nt++){ Ch[0][nt]=MFMA(ah,BUhi[nt][2],Ch[0][nt],0,0,0); Ch[0][nt]=MFMA(ah,BUlo[nt][2],Ch[0][nt],0,0,0); Ch[0][nt]=MFMA(al,BUhi[nt][2],Ch[0][nt],0,0,0); }
      unpackg(g06,g07,ah,al);
      #pragma unroll
      for(int nt=0;nt<2;nt++){ Ch[0][nt]=MFMA(ah,BUhi[nt][3],Ch[0][nt],0,0,0); Ch[0][nt]=MFMA(ah,BUlo[nt][3],Ch[0][nt],0,0,0); Ch[0][nt]=MFMA(al,BUhi[nt][3],Ch[0][nt],0,0,0); }
      // mi = 1
      unpackg(g10,g11,ah,al);
      #pragma unroll
      for(int nt=0;nt<2;nt++){ Ch[1][nt]=MFMA(ah,BUhi[nt][0],Ch[1][nt],0,0,0); Ch[1][nt]=MFMA(ah,BUlo[nt][0],Ch[1][nt],0,0,0); Ch[1][nt]=MFMA(al,BUhi[nt][0],Ch[1][nt],0,0,0); }
      unpackg(g12,g13,ah,al);
      #pragma unroll
      for(int nt=0;nt<2;nt++){ Ch[1][nt]=MFMA(ah,BUhi[nt][1],Ch[1][nt],0,0,0); Ch[1][nt]=MFMA(ah,BUlo[nt][1],Ch[1][nt],0,0,0); Ch[1][nt]=MFMA(al,BUhi[nt][1],Ch[1][nt],0,0,0); }
      unpackg(g14,g15,ah,al);
      #pragma unroll
      for(int nt=0;nt<2;nt++){ Ch[1][nt]=MFMA(ah,BUhi[nt][2],Ch[1][nt],0,0,0); Ch[1][nt]=MFMA(ah,BUlo[nt][2],Ch[1][nt],0,0,0); Ch[1][nt]=MFMA(al,BUhi[nt][2],Ch[1][nt],0,0,0); }
      unpackg(g16,g17,ah,al);
      #pragma unroll
      for(int nt=0;nt<2;nt++){ Ch[1][nt]=MFMA(ah,BUhi[nt][3],Ch[1][nt],0,0,0); Ch[1][nt]=MFMA(ah,BUlo[nt][3],Ch[1][nt],0,0,0); Ch[1][nt]=MFMA(al,BUhi[nt][3],Ch[1][nt],0,0,0); }
    }
    #pragma unroll
    for(int mi=0;mi<2;mi++)
      #pragma unroll
      for(int nt=0;nt<2;nt++)
        red[q][2*m2+mi][nt][lane] = Ch[mi][nt];
    __syncthreads();
    if(u < 4){
      const int w = u;
      f32x4 hgf[2];
      #pragma unroll
      for(int nt=0; nt<2; nt++)
        hgf[nt] = red[0][w][nt][lane] + red[1][w][nt][lane]
                + red[2][w][nt][lane] + red[3][w][nt][lane];
      float p0[4], p0s[4];
      #pragma unroll
      for(int r=0;r<4;r++) p0[r] = xgf[0][r] + hgf[0][r] + bsum0;
      #pragma unroll
      for(int r=0;r<4;r++) p0s[r] = __shfl_xor(p0[r], 8, 64);
      if(col < 8){
        #pragma unroll
        for(int r=0;r<4;r++){
          int b = w*16 + lg*4 + r;
          float rg = __builtin_amdgcn_rcpf(1.f + __expf(-p0[r]));
          float ug = __builtin_amdgcn_rcpf(1.f + __expf(-p0s[r]));
          float hn = hgf[1][r] + bun;
          float z  = xgf[1][r] + bwn + rg*hn;
          z = fminf(fmaxf(z, -15.f), 15.f);
          float e  = __expf(2.f*z);
          float nn = (e - 1.f) * __builtin_amdgcn_rcpf(e + 1.f);   // tanh(z)
          float hnew = ug*hreg[r] + (1.f - ug)*nn;
          hreg[r] = hnew;
          on[r]   = hnew;
          unsigned short h16 = f2bf(hnew);
          unsigned short l16 = f2bf(hnew - bf2f(h16));
          __hip_atomic_store(&hw[(size_t)b*HH + j0 + col],
                             ((unsigned)h16 << 16) | (unsigned)l16,
                             __ATOMIC_RELAXED, __HIP_MEMORY_SCOPE_AGENT);
        }
      }
    }
    bar++;
    __syncthreads();   // per-wave vmcnt(0) drain: all h-stores at LLC before flag
    if(tid == 0)
      __hip_atomic_store(&flags[bid], bar, __ATOMIC_RELAXED, __HIP_MEMORY_SCOPE_AGENT);
  };

  // ---- relaxed barrier wait: lane i watches flags[i] ----
  auto poll = [&](){
    unsigned tgt = bar;
    while(true){
      unsigned f = __hip_atomic_load(&flags[lane], __ATOMIC_RELAXED, __HIP_MEMORY_SCOPE_AGENT);
      if(__all((int)(f >= tgt))) break;
      __builtin_amdgcn_s_sleep(1);
    }
    __builtin_amdgcn_sched_barrier(0);
    asm volatile("" ::: "memory");
  };

  f32x4 xgf[2] = {(f32x4){0,0,0,0},(f32x4){0,0,0,0}};
  f32x4 xgn[2] = {(f32x4){0,0,0,0},(f32x4){0,0,0,0}};
  float on0[4] = {0,0,0,0}, on1[4] = {0,0,0,0};
  compute_xg(0, xgf);

  for(int t=0; t<TT; t++){
    // ---- layer 0: read buf0, write buf1 ----
    run_cell(hbuf, hbuf + (size_t)BB*HH, xgf, on0);
    if(u < 4 && col < 8){
      #pragma unroll
      for(int r=0;r<4;r++){
        int b = u*16 + lg*4 + r;
        out[((size_t)(2*t)*BB + b)*HH + j0 + col] = on0[r];
      }
    }
    if(t+1 < TT) compute_xg(t+1, xgn);
    poll();
    // ---- layer 1: read buf1, write buf0 (same xg) ----
    run_cell(hbuf + (size_t)BB*HH, hbuf, xgf, on1);
    if(u < 4 && col < 8){
      #pragma unroll
      for(int r=0;r<4;r++){
        int b = u*16 + lg*4 + r;
        out[((size_t)(2*t+1)*BB + b)*HH + j0 + col] = on1[r];
      }
    }
    poll();
    xgf[0] = xgn[0]; xgf[1] = xgn[1];
  }
}

extern "C" void kernel_launch(void* const* d_in, const int* in_sizes, int n_in,
                              void* d_out, int out_size, void* d_ws, size_t ws_size,
                              hipStream_t stream) {
  const float* x  = (const float*)d_in[0];
  const float* Wm = (const float*)d_in[1];
  const float* bW = (const float*)d_in[2];
  const float* Um = (const float*)d_in[3];
  const float* bU = (const float*)d_in[4];
  float* out = (float*)d_out;

  // ws layout: hbuf[2][64][512] u32 (256 KB) + flags[64] u32
  unsigned* hbuf  = (unsigned*)d_ws;
  unsigned* flags = (unsigned*)((char*)d_ws + 2*BB*HH*sizeof(unsigned));
  (void)hipMemsetAsync(d_ws, 0, 2*BB*HH*sizeof(unsigned) + 256, stream);

  gru_scan<<<NBLK, 512, 0, stream>>>(x, Wm, bW, Um, bU, out, hbuf, flags);
}